// Round 15
// baseline (324.917 us; speedup 1.0000x reference)
//
#include <hip/hip_runtime.h>
#include <hip/hip_bf16.h>

#define SEQ 2048
#define DM  2048
#define NH  16
#define DE  128
#define DR  64
#define LDK 136   // K-tile LDS row stride (elems)
#define LDV 36    // V^T-tile LDS row stride
#define LDP 36    // P-tile LDS row stride

typedef __attribute__((ext_vector_type(8))) short bf16x8;
typedef __attribute__((ext_vector_type(4))) float f32x4;

__device__ __forceinline__ unsigned short f2bf(float f) {
  unsigned u = __float_as_uint(f);
  u += 0x7fff + ((u >> 16) & 1);   // RNE
  return (unsigned short)(u >> 16);
}
__device__ __forceinline__ float bf2f(unsigned short h) {
  return __uint_as_float((unsigned)h << 16);
}

// async global->LDS, 16B per lane. LDS dest = wave-uniform base + lane*16.
__device__ __forceinline__ void gld16(const unsigned short* g, unsigned short* l) {
  __builtin_amdgcn_global_load_lds(
      (const __attribute__((address_space(1))) unsigned int*)g,
      (__attribute__((address_space(3))) unsigned int*)l, 16, 0, 0);
}

// ---------------- fp32 -> (hi, lo) bf16 split ----------------
__global__ void k_split(const float* __restrict__ in, unsigned short* __restrict__ hi,
                        unsigned short* __restrict__ lo, int n4) {
  int i = blockIdx.x * blockDim.x + threadIdx.x;
  int stride = gridDim.x * blockDim.x;
  for (int idx = i; idx < n4; idx += stride) {
    float4 v = ((const float4*)in)[idx];
    ushort4 h, l;
    h.x = f2bf(v.x); l.x = f2bf(v.x - bf2f(h.x));
    h.y = f2bf(v.y); l.y = f2bf(v.y - bf2f(h.y));
    h.z = f2bf(v.z); l.z = f2bf(v.z - bf2f(h.z));
    h.w = f2bf(v.w); l.w = f2bf(v.w - bf2f(h.w));
    ((ushort4*)hi)[idx] = h;
    ((ushort4*)lo)[idx] = l;
  }
}

// ---------------- fused weight prep: q/k split-transpose, v transpose, o transpose ----------------
__global__ void k_prep_all(const float* __restrict__ q, const float* __restrict__ k,
                           const float* __restrict__ v, const float* __restrict__ o,
                           unsigned short* __restrict__ wqh, unsigned short* __restrict__ wql,
                           unsigned short* __restrict__ wkh, unsigned short* __restrict__ wkl,
                           unsigned short* __restrict__ wvh, unsigned short* __restrict__ otb) {
  __shared__ float tile[32][33];
  int f = blockIdx.x;
  int tx = threadIdx.x, ty = threadIdx.y;
  if (f < 12288) {
    int z = f >> 8;            // 0..47
    int rem = f & 255;         // 64 y-tiles x 4 x-tiles
    int ry = rem >> 2, rx = rem & 3;
    int which = z >> 4, h = z & 15;
    const float* in = (which == 0) ? q : (which == 1) ? k : v;
    size_t bo = (size_t)h * DM * DE;
    int r0 = ry * 32, c0 = rx * 32;
    #pragma unroll
    for (int i = 0; i < 32; i += 8)
      tile[ty + i][tx] = in[bo + (size_t)(r0 + ty + i) * DE + (c0 + tx)];
    __syncthreads();
    #pragma unroll
    for (int i = 0; i < 32; i += 8) {
      float vv = tile[tx][ty + i];
      unsigned short hh = f2bf(vv);
      size_t oidx = bo + (size_t)(c0 + ty + i) * DM + (r0 + tx);
      if (which == 0)      { wqh[oidx] = hh; wql[oidx] = f2bf(vv - bf2f(hh)); }
      else if (which == 1) { wkh[oidx] = hh; wkl[oidx] = f2bf(vv - bf2f(hh)); }
      else                 { wvh[oidx] = hh; }
    }
  } else {
    int rem = f - 12288;       // o: [2048 n][2048 d] -> otb[d][n]
    int ry = rem >> 6, rx = rem & 63;
    int r0 = ry * 32, c0 = rx * 32;
    #pragma unroll
    for (int i = 0; i < 32; i += 8)
      tile[ty + i][tx] = o[(size_t)(r0 + ty + i) * DM + (c0 + tx)];
    __syncthreads();
    #pragma unroll
    for (int i = 0; i < 32; i += 8)
      otb[(size_t)(c0 + ty + i) * DM + (r0 + tx)] = f2bf(tile[tx][ty + i]);
  }
}

// ---------------- RoPE tables ----------------
__global__ void k_rope_tables(const float* __restrict__ theta_p,
                              float* __restrict__ cost, float* __restrict__ sint) {
  int s = blockIdx.x, j = threadIdx.x;
  float theta = theta_p[0];
  float rate = powf(theta, -(float)j * (1.0f / (float)DR));
  float ang = (float)s * rate;
  cost[s * DR + j] = cosf(ang);
  sint[s * DR + j] = sinf(ang);
}

// ---------------- merged q/k/v projection GEMM, 2-phase dbuf, 2x2 wave decomp ----------------
__launch_bounds__(256)
__global__ void k_projall(const unsigned short* __restrict__ xh, const unsigned short* __restrict__ xl,
                          const unsigned short* __restrict__ wqh, const unsigned short* __restrict__ wql,
                          const unsigned short* __restrict__ wkh, const unsigned short* __restrict__ wkl,
                          const unsigned short* __restrict__ wvh,
                          unsigned short* __restrict__ rqh, unsigned short* __restrict__ rql,
                          unsigned short* __restrict__ rkh, unsigned short* __restrict__ rkl,
                          unsigned short* __restrict__ vstt,
                          const float* __restrict__ cost, const float* __restrict__ sint) {
  __shared__ unsigned short Ahs[2][128 * 32];
  __shared__ unsigned short Als[2][128 * 32];
  __shared__ unsigned short Bhs[2][128 * 32];
  __shared__ unsigned short Bls[2][128 * 32];
  int mt = blockIdx.x;
  int mat = blockIdx.y >> 4, h = blockIdx.y & 15;
  bool split = (mat < 2);
  const unsigned short* wph = (mat == 0 ? wqh : (mat == 1 ? wkh : wvh)) + (size_t)h * DE * DM;
  const unsigned short* wpl = (mat == 0 ? wql : wkl) + (size_t)h * DE * DM;  // unused if mat==2
  int m0 = mt * 128;
  int tid = threadIdx.x, lane = tid & 63, wid = tid >> 6;
  int wr = wid >> 1, wc = wid & 1;

  f32x4 zero = {0.f, 0.f, 0.f, 0.f};
  f32x4 acc[4][4];
  #pragma unroll
  for (int i = 0; i < 4; ++i)
    #pragma unroll
    for (int j = 0; j < 4; ++j) acc[i][j] = zero;

  auto STAGE = [&](int buf, int k0) {
    #pragma unroll
    for (int p = 0; p < 2; ++p) {
      int r = p * 64 + wid * 16 + (lane >> 2);
      int c = ((lane & 3) ^ ((r >> 1) & 3)) * 8;     // inverse-swizzled global chunk
      int ld = r * 32 + (lane & 3) * 8;              // linear LDS dest
      gld16(&xh[(size_t)(m0 + r) * DM + k0 + c], &Ahs[buf][ld]);
      gld16(&wph[(size_t)r * DM + k0 + c], &Bhs[buf][ld]);
      if (split) {
        gld16(&xl[(size_t)(m0 + r) * DM + k0 + c], &Als[buf][ld]);
        gld16(&wpl[(size_t)r * DM + k0 + c], &Bls[buf][ld]);
      }
    }
  };

  const int NT = DM / 32;  // 64
  STAGE(0, 0);
  int cl_ = lane & 15;
  int chunk = lane >> 4;
  #pragma unroll 2
  for (int t = 0; t < NT; ++t) {
    int buf = t & 1;
    __syncthreads();                       // drains vmcnt(0): tile t staged; prev reads done
    if (t + 1 < NT) STAGE(buf ^ 1, (t + 1) * 32);   // loads fly during compute
    bf16x8 ah[4], al[4], bh[4], bl[4];
    #pragma unroll
    for (int mf = 0; mf < 4; ++mf) {
      int row = wr * 64 + mf * 16 + cl_;
      int off = row * 32 + ((chunk ^ ((row >> 1) & 3)) * 8);
      ah[mf] = *(const bf16x8*)&Ahs[buf][off];
      if (split) al[mf] = *(const bf16x8*)&Als[buf][off];
    }
    #pragma unroll
    for (int nf = 0; nf < 4; ++nf) {
      int nfi = wc * 2 + (nf & 1) + (nf >> 1) * 4;
      int row = nfi * 16 + cl_;
      int off = row * 32 + ((chunk ^ ((row >> 1) & 3)) * 8);
      bh[nf] = *(const bf16x8*)&Bhs[buf][off];
      if (split) bl[nf] = *(const bf16x8*)&Bls[buf][off];
    }
    if (split) {
      #pragma unroll
      for (int mf = 0; mf < 4; ++mf)
        #pragma unroll
        for (int nf = 0; nf < 4; ++nf) {
          acc[mf][nf] = __builtin_amdgcn_mfma_f32_16x16x32_bf16(ah[mf], bh[nf], acc[mf][nf], 0, 0, 0);
          acc[mf][nf] = __builtin_amdgcn_mfma_f32_16x16x32_bf16(al[mf], bh[nf], acc[mf][nf], 0, 0, 0);
          acc[mf][nf] = __builtin_amdgcn_mfma_f32_16x16x32_bf16(ah[mf], bl[nf], acc[mf][nf], 0, 0, 0);
        }
    } else {
      #pragma unroll
      for (int mf = 0; mf < 4; ++mf)
        #pragma unroll
        for (int nf = 0; nf < 4; ++nf)
          acc[mf][nf] = __builtin_amdgcn_mfma_f32_16x16x32_bf16(ah[mf], bh[nf], acc[mf][nf], 0, 0, 0);
    }
  }

  int cl = lane & 15, rl = (lane >> 4) * 4;
  if (mat == 2) {
    #pragma unroll
    for (int mf = 0; mf < 4; ++mf)
      #pragma unroll
      for (int nf = 0; nf < 4; ++nf) {
        int nfi = wc * 2 + (nf & 1) + (nf >> 1) * 4;
        #pragma unroll
        for (int j = 0; j < 4; ++j) {
          int s = m0 + wr * 64 + mf * 16 + rl + j;
          int e = nfi * 16 + cl;
          vstt[((size_t)h * DE + e) * SEQ + s] = f2bf(acc[mf][nf][j]);
        }
      }
  } else {
    unsigned short* oh = (mat == 0) ? rqh : rkh;
    unsigned short* ol = (mat == 0) ? rql : rkl;
    const float qsc = 0.2973017787506803f;  // 128^-0.25
    #pragma unroll
    for (int mf = 0; mf < 4; ++mf)
      #pragma unroll
      for (int nf = 0; nf < 2; ++nf)     // pair (nf, nf+2): cols e and e+64
        #pragma unroll
        for (int j = 0; j < 4; ++j) {
          int s = m0 + wr * 64 + mf * 16 + rl + j;
          int e = wc * 32 + (nf & 1) * 16 + cl;  // 0..63
          float x1 = acc[mf][nf][j];
          float x2 = acc[mf][nf + 2][j];
          float c  = cost[s * DR + e];
          float sn = sint[s * DR + e];
          float v1 = (c * x1 - sn * x2) * qsc;
          float v2 = (sn * x1 + c * x2) * qsc;
          size_t i1 = ((size_t)h * SEQ + s) * DE + e;
          size_t i2 = i1 + DR;
          unsigned short h1 = f2bf(v1), h2 = f2bf(v2);
          oh[i1] = h1; ol[i1] = f2bf(v1 - bf2f(h1));
          oh[i2] = h2; ol[i2] = f2bf(v2 - bf2f(h2));
        }
  }
}

// ---------------- causal flash attention: QB=32/KVBLK=32, 128-thr blocks, 4 blocks/CU ----------------
// Grid 1024. XCD-head grouping: h = ((bid&7)<<1)|((bid>>3)&1) -> each head's 64 blocks on one
// XCD (2 heads x 1.5MB KV = 3MB < 4MiB L2). Balanced LPT: qt = g<32 ? 63-g : g-32 -> every
// CU's 4 blocks sum to 130 tile-iters. Named prefetch regs (rule #20). Defer-max (T13).
#define LOADKV(t0)                                                        \
  pkh0 = *(const int4*)&Kh[(size_t)((t0) + sk_r     ) * DE + sk_c];       \
  pkh1 = *(const int4*)&Kh[(size_t)((t0) + sk_r +  8) * DE + sk_c];       \
  pkh2 = *(const int4*)&Kh[(size_t)((t0) + sk_r + 16) * DE + sk_c];       \
  pkh3 = *(const int4*)&Kh[(size_t)((t0) + sk_r + 24) * DE + sk_c];       \
  pkl0 = *(const int4*)&Kl[(size_t)((t0) + sk_r     ) * DE + sk_c];       \
  pkl1 = *(const int4*)&Kl[(size_t)((t0) + sk_r +  8) * DE + sk_c];       \
  pkl2 = *(const int4*)&Kl[(size_t)((t0) + sk_r + 16) * DE + sk_c];       \
  pkl3 = *(const int4*)&Kl[(size_t)((t0) + sk_r + 24) * DE + sk_c];       \
  pvv0 = *(const int4*)&Vt[(size_t)(sv_r     ) * SEQ + (t0) + sv_c];      \
  pvv1 = *(const int4*)&Vt[(size_t)(sv_r + 32) * SEQ + (t0) + sv_c];      \
  pvv2 = *(const int4*)&Vt[(size_t)(sv_r + 64) * SEQ + (t0) + sv_c];      \
  pvv3 = *(const int4*)&Vt[(size_t)(sv_r + 96) * SEQ + (t0) + sv_c];

#define STOREKV()                                                         \
  *(int4*)&Khi[(sk_r     ) * LDK + sk_c] = pkh0;                          \
  *(int4*)&Khi[(sk_r +  8) * LDK + sk_c] = pkh1;                          \
  *(int4*)&Khi[(sk_r + 16) * LDK + sk_c] = pkh2;                          \
  *(int4*)&Khi[(sk_r + 24) * LDK + sk_c] = pkh3;                          \
  *(int4*)&Klo[(sk_r     ) * LDK + sk_c] = pkl0;                          \
  *(int4*)&Klo[(sk_r +  8) * LDK + sk_c] = pkl1;                          \
  *(int4*)&Klo[(sk_r + 16) * LDK + sk_c] = pkl2;                          \
  *(int4*)&Klo[(sk_r + 24) * LDK + sk_c] = pkl3;                          \
  *(int4*)&Vtl[(sv_r     ) * LDV + sv_c] = pvv0;                          \
  *(int4*)&Vtl[(sv_r + 32) * LDV + sv_c] = pvv1;                          \
  *(int4*)&Vtl[(sv_r + 64) * LDV + sv_c] = pvv2;                          \
  *(int4*)&Vtl[(sv_r + 96) * LDV + sv_c] = pvv3;

__launch_bounds__(128, 2)
__global__ void k_attn(const unsigned short* __restrict__ rqh, const unsigned short* __restrict__ rql,
                       const unsigned short* __restrict__ rkh, const unsigned short* __restrict__ rkl,
                       const unsigned short* __restrict__ vstt,
                       unsigned short* __restrict__ yb) {
  __shared__ unsigned short Khi[32 * LDK];
  __shared__ unsigned short Klo[32 * LDK];
  __shared__ unsigned short Vtl[128 * LDV];
  __shared__ unsigned short Pl[32 * LDP];
  int bid = blockIdx.x;
  int h = ((bid & 7) << 1) | ((bid >> 3) & 1);   // XCD-head grouping
  int g = bid >> 4;                               // 0..63
  int qt = (g < 32) ? (63 - g) : (g - 32);        // balanced LPT
  int m0 = qt * 32;
  int tid = threadIdx.x, lane = tid & 63, wid = tid >> 6;   // wid 0..1
  const unsigned short* Qh = rqh + (size_t)h * SEQ * DE;
  const unsigned short* Ql = rql + (size_t)h * SEQ * DE;
  const unsigned short* Kh = rkh + (size_t)h * SEQ * DE;
  const unsigned short* Kl = rkl + (size_t)h * SEQ * DE;
  const unsigned short* Vt = vstt + (size_t)h * DE * SEQ;
  int cl = lane & 15, hi = lane >> 4;

  bf16x8 qfh[4], qfl[4];
  {
    int qrow = m0 + wid * 16 + cl;
    #pragma unroll
    for (int ks = 0; ks < 4; ++ks) {
      qfh[ks] = *(const bf16x8*)&Qh[(size_t)qrow * DE + ks * 32 + hi * 8];
      qfl[ks] = *(const bf16x8*)&Ql[(size_t)qrow * DE + ks * 32 + hi * 8];
    }
  }

  f32x4 zero = {0.f, 0.f, 0.f, 0.f};
  f32x4 acc[8];
  #pragma unroll
  for (int nf = 0; nf < 8; ++nf) acc[nf] = zero;
  float mrow[4], lrow[4];
  #pragma unroll
  for (int j = 0; j < 4; ++j) { mrow[j] = -3e38f; lrow[j] = 0.f; }

  int sk_r = tid >> 4, sk_c = (tid & 15) * 8;   // K staging: 8 rows x 16 slots
  int sv_r = tid >> 2, sv_c = (tid & 3) * 8;    // V staging: 32 rows x 4 slots

  int4 pkh0, pkh1, pkh2, pkh3, pkl0, pkl1, pkl2, pkl3, pvv0, pvv1, pvv2, pvv3;

  int ntiles = qt + 1;
  LOADKV(0)
  for (int t = 0; t < ntiles; ++t) {
    int t0 = t * 32;
    STOREKV()
    __syncthreads();
    if (t + 1 < ntiles) { LOADKV(t0 + 32) }

    f32x4 sacc[2];
    #pragma unroll
    for (int tf = 0; tf < 2; ++tf) sacc[tf] = zero;
    __builtin_amdgcn_s_setprio(1);
    #pragma unroll
    for (int ks = 0; ks < 4; ++ks) {
      int kk = ks * 32 + hi * 8;
      #pragma unroll
      for (int tf = 0; tf < 2; ++tf) {
        int r = (tf * 16 + cl) * LDK + kk;
        bf16x8 bh = *(const bf16x8*)&Khi[r];
        bf16x8 bl = *(const bf16x8*)&Klo[r];
        sacc[tf] = __builtin_amdgcn_mfma_f32_16x16x32_bf16(qfh[ks], bh, sacc[tf], 0, 0, 0);
        sacc[tf] = __builtin_amdgcn_mfma_f32_16x16x32_bf16(qfl[ks], bh, sacc[tf], 0, 0, 0);
        sacc[tf] = __builtin_amdgcn_mfma_f32_16x16x32_bf16(qfh[ks], bl, sacc[tf], 0, 0, 0);
      }
    }
    __builtin_amdgcn_s_setprio(0);
    if (t == ntiles - 1) {
      int sb = m0 + wid * 16 + hi * 4;
      #pragma unroll
      for (int tf = 0; tf < 2; ++tf) {
        int tc = t0 + tf * 16 + cl;
        #pragma unroll
        for (int j = 0; j < 4; ++j)
          if (tc > sb + j) sacc[tf][j] = -3e38f;
      }
    }
    // row maxima (always computed for the defer test)
    float mxa[4];
    #pragma unroll
    for (int j = 0; j < 4; ++j) {
      float mx = fmaxf(sacc[0][j], sacc[1][j]);
      mx = fmaxf(mx, __shfl_xor(mx, 1));
      mx = fmaxf(mx, __shfl_xor(mx, 2));
      mx = fmaxf(mx, __shfl_xor(mx, 4));
      mx = fmaxf(mx, __shfl_xor(mx, 8));
      mxa[j] = mx;
    }
    bool need = (mxa[0] > mrow[0] + 8.f) || (mxa[1] > mrow[1] + 8.f) ||
                (mxa[2] > mrow[2] + 8.f) || (mxa[3] > mrow[3] + 8.f);
    if (__any(need)) {
      #pragma unroll
      for (int j = 0; j < 4; ++j) {
        float mnew = fmaxf(mrow[j], mxa[j]);
        float sc = __expf(mrow[j] - mnew);
        float sum = 0.f;
        #pragma unroll
        for (int tf = 0; tf < 2; ++tf) {
          float p = __expf(sacc[tf][j] - mnew);
          sacc[tf][j] = p;
          sum += p;
        }
        sum += __shfl_xor(sum, 1);
        sum += __shfl_xor(sum, 2);
        sum += __shfl_xor(sum, 4);
        sum += __shfl_xor(sum, 8);
        lrow[j] = lrow[j] * sc + sum;
        mrow[j] = mnew;
        #pragma unroll
        for (int nf = 0; nf < 8; ++nf) acc[nf][j] *= sc;
      }
    } else {
      #pragma unroll
      for (int j = 0; j < 4; ++j) {
        float sum = 0.f;
        #pragma unroll
        for (int tf = 0; tf < 2; ++tf) {
          float p = __expf(sacc[tf][j] - mrow[j]);
          sacc[tf][j] = p;
          sum += p;
        }
        sum += __shfl_xor(sum, 1);
        sum += __shfl_xor(sum, 2);
        sum += __shfl_xor(sum, 4);
        sum += __shfl_xor(sum, 8);
        lrow[j] += sum;
      }
    }
    #pragma unroll
    for (int tf = 0; tf < 2; ++tf)
      #pragma unroll
      for (int j = 0; j < 4; ++j)
        Pl[(wid * 16 + hi * 4 + j) * LDP + tf * 16 + cl] = f2bf(sacc[tf][j]);
    __builtin_amdgcn_s_setprio(1);
    {
      int kk = hi * 8;
      bf16x8 a = *(const bf16x8*)&Pl[(wid * 16 + cl) * LDP + kk];
      #pragma unroll
      for (int nf = 0; nf < 8; ++nf) {
        bf16x8 b = *(const bf16x8*)&Vtl[(nf * 16 + cl) * LDV + kk];
        acc[nf] = __builtin_amdgcn_mfma_f32_16x16x32_bf16(a, b, acc[nf], 0, 0, 0);
      }
    }
    __builtin_amdgcn_s_setprio(0);
    __syncthreads();
  }

  #pragma unroll
  for (int j = 0; j < 4; ++j) {
    float inv = 1.0f / lrow[j];
    #pragma unroll
    for (int nf = 0; nf < 8; ++nf) acc[nf][j] *= inv;
  }
  #pragma unroll
  for (int nf = 0; nf < 8; ++nf)
    #pragma unroll
    for (int j = 0; j < 4; ++j) {
      int s = m0 + wid * 16 + hi * 4 + j;
      int e = nf * 16 + cl;
      yb[(size_t)s * DM + h * DE + e] = f2bf(acc[nf][j]);
    }
}

// ---------------- output projection GEMM (fp32 out), 2-phase dbuf BK=32, 2x2 decomp ----------------
__launch_bounds__(256)
__global__ void k_out(const unsigned short* __restrict__ yb,
                      const unsigned short* __restrict__ otb,
                      float* __restrict__ z) {
  __shared__ unsigned short Ahs[2][128 * 32];
  __shared__ unsigned short Bhs[2][128 * 32];
  int m0 = blockIdx.x * 128, n0 = blockIdx.y * 128;
  int tid = threadIdx.x, lane = tid & 63, wid = tid >> 6;
  int wr = wid >> 1, wc = wid & 1;
  f32x4 zero = {0.f, 0.f, 0.f, 0.f};
  f32x4 acc[4][4];
  #pragma unroll
  for (int i = 0; i < 4; ++i)
    #pragma unroll
    for (int j = 0; j < 4; ++j) acc[i][j] = zero;

  auto STAGE = [&](int buf, int k0) {
    #pragma unroll
    for (int p = 0; p < 2; ++p) {
      int r = p * 64 + wid * 16 + (lane >> 2);
      int c = ((lane & 3) ^ ((r >> 1) & 3)) * 8;
      int ld = r * 32 + (lane & 3) * 8;
      gld16(&yb[(size_t)(m0 + r) * DM + k0 + c], &Ahs[buf][ld]);
      gld16(&otb[(size_t)(n0 + r) * DM + k0 + c], &Bhs[buf][ld]);
    }
  };

  const int NT = DM / 32;
  STAGE(0, 0);
  int cl_ = lane & 15;
  int chunk = lane >> 4;
  #pragma unroll 2
  for (int t = 0; t < NT; ++t) {
    int buf = t & 1;
    __syncthreads();
    if (t + 1 < NT) STAGE(buf ^ 1, (t + 1) * 32);
    bf16x8 a[4], b[4];
    #pragma unroll
    for (int mf = 0; mf < 4; ++mf) {
      int row = wr * 64 + mf * 16 + cl_;
      a[mf] = *(const bf16x8*)&Ahs[buf][row * 32 + ((chunk ^ ((row >> 1) & 3)) * 8)];
    }
    #pragma unroll
    for (int nf = 0; nf < 4; ++nf) {
      int nfi = wc * 2 + (nf & 1) + (nf >> 1) * 4;
      int row = nfi * 16 + cl_;
      b[nf] = *(const bf16x8*)&Bhs[buf][row * 32 + ((chunk ^ ((row >> 1) & 3)) * 8)];
    }
    #pragma unroll
    for (int mf = 0; mf < 4; ++mf)
      #pragma unroll
      for (int nf = 0; nf < 4; ++nf)
        acc[mf][nf] = __builtin_amdgcn_mfma_f32_16x16x32_bf16(a[mf], b[nf], acc[mf][nf], 0, 0, 0);
  }
  int cl = lane & 15, rl = (lane >> 4) * 4;
  #pragma unroll
  for (int mf = 0; mf < 4; ++mf)
    #pragma unroll
    for (int nf = 0; nf < 4; ++nf) {
      int nfi = wc * 2 + (nf & 1) + (nf >> 1) * 4;
      #pragma unroll
      for (int j = 0; j < 4; ++j) {
        int s = m0 + wr * 64 + mf * 16 + rl + j;
        int d = n0 + nfi * 16 + cl;
        z[(size_t)s * DM + d] = acc[mf][nf][j];
      }
    }
}

extern "C" void kernel_launch(void* const* d_in, const int* in_sizes, int n_in,
                              void* d_out, int out_size, void* d_ws, size_t ws_size,
                              hipStream_t stream) {
  const float* x  = (const float*)d_in[0];
  const float* q  = (const float*)d_in[1];
  const float* k  = (const float*)d_in[2];
  const float* v  = (const float*)d_in[3];
  const float* o  = (const float*)d_in[4];
  const float* th = (const float*)d_in[5];
  float* z = (float*)d_out;
  char* ws = (char*)d_ws;
  const size_t MB = 1024 * 1024;
  unsigned short* xh  = (unsigned short*)(ws);            // 0
  unsigned short* xl  = (unsigned short*)(ws + 8 * MB);   // 8
  unsigned short* wqh = (unsigned short*)(ws + 16 * MB);  // 16
  unsigned short* wql = (unsigned short*)(ws + 24 * MB);  // 24
  unsigned short* wkh = (unsigned short*)(ws + 32 * MB);  // 32
  unsigned short* wkl = (unsigned short*)(ws + 40 * MB);  // 40
  unsigned short* wvh = (unsigned short*)(ws + 48 * MB);  // 48
  unsigned short* rqh = (unsigned short*)(ws + 56 * MB);  // 56
  unsigned short* rql = (unsigned short*)(ws + 64 * MB);  // 64
  unsigned short* rkh = (unsigned short*)(ws + 72 * MB);  // 72
  unsigned short* rkl = (unsigned short*)(ws + 80 * MB);  // 80
  unsigned short* vst = (unsigned short*)(ws + 88 * MB);  // 88
  float* cost = (float*)(ws + 96 * MB);                   // 96
  float* sint = (float*)(ws + 96 * MB + 512 * 1024);
  unsigned short* otb = (unsigned short*)(ws + 98 * MB);  // 98 (written by prep, read by k_out)
  // alias over dead weight buffer (stream-ordered):
  unsigned short* yb  = (unsigned short*)(ws + 16 * MB);  // over wqh, written after proj

  dim3 tb(32, 8);
  k_rope_tables<<<SEQ, DR, 0, stream>>>(th, cost, sint);
  k_split<<<2048, 256, 0, stream>>>(x, xh, xl, SEQ * DM / 4);
  k_prep_all<<<16384, tb, 0, stream>>>(q, k, v, o, wqh, wql, wkh, wkl, wvh, otb);
  k_projall<<<dim3(16, 48), 256, 0, stream>>>(xh, xl, wqh, wql, wkh, wkl, wvh,
                                              rqh, rql, rkh, rkl, vst, cost, sint);
  k_attn<<<1024, 128, 0, stream>>>(rqh, rql, rkh, rkl, vst, yb);
  k_out<<<dim3(16, 16), 256, 0, stream>>>(yb, otb, z);
}

// Round 16
// 311.631 us; speedup vs baseline: 1.0426x; 1.0426x over previous
//
#include <hip/hip_runtime.h>
#include <hip/hip_bf16.h>

#define SEQ 2048
#define DM  2048
#define NH  16
#define DE  128
#define DR  64
#define LDT 72    // padded LDS row stride (elements) — k_attn
#define LDK 136

typedef __attribute__((ext_vector_type(8))) short bf16x8;
typedef __attribute__((ext_vector_type(4))) float f32x4;

__device__ __forceinline__ unsigned short f2bf(float f) {
  unsigned u = __float_as_uint(f);
  u += 0x7fff + ((u >> 16) & 1);   // RNE
  return (unsigned short)(u >> 16);
}
__device__ __forceinline__ float bf2f(unsigned short h) {
  return __uint_as_float((unsigned)h << 16);
}

// async global->LDS, 16B per lane. LDS dest = wave-uniform base + lane*16.
__device__ __forceinline__ void gld16(const unsigned short* g, unsigned short* l) {
  __builtin_amdgcn_global_load_lds(
      (const __attribute__((address_space(1))) unsigned int*)g,
      (__attribute__((address_space(3))) unsigned int*)l, 16, 0, 0);
}

// ---------------- fp32 -> (hi, lo) bf16 split ----------------
__global__ void k_split(const float* __restrict__ in, unsigned short* __restrict__ hi,
                        unsigned short* __restrict__ lo, int n4) {
  int i = blockIdx.x * blockDim.x + threadIdx.x;
  int stride = gridDim.x * blockDim.x;
  for (int idx = i; idx < n4; idx += stride) {
    float4 v = ((const float4*)in)[idx];
    ushort4 h, l;
    h.x = f2bf(v.x); l.x = f2bf(v.x - bf2f(h.x));
    h.y = f2bf(v.y); l.y = f2bf(v.y - bf2f(h.y));
    h.z = f2bf(v.z); l.z = f2bf(v.z - bf2f(h.z));
    h.w = f2bf(v.w); l.w = f2bf(v.w - bf2f(h.w));
    ((ushort4*)hi)[idx] = h;
    ((ushort4*)lo)[idx] = l;
  }
}

// ---------------- fused weight prep: q/k split-transpose, v transpose, o transpose ----------------
__global__ void k_prep_all(const float* __restrict__ q, const float* __restrict__ k,
                           const float* __restrict__ v, const float* __restrict__ o,
                           unsigned short* __restrict__ wqh, unsigned short* __restrict__ wql,
                           unsigned short* __restrict__ wkh, unsigned short* __restrict__ wkl,
                           unsigned short* __restrict__ wvh, unsigned short* __restrict__ otb) {
  __shared__ float tile[32][33];
  int f = blockIdx.x;
  int tx = threadIdx.x, ty = threadIdx.y;
  if (f < 12288) {
    int z = f >> 8;            // 0..47
    int rem = f & 255;         // 64 y-tiles x 4 x-tiles
    int ry = rem >> 2, rx = rem & 3;
    int which = z >> 4, h = z & 15;
    const float* in = (which == 0) ? q : (which == 1) ? k : v;
    size_t bo = (size_t)h * DM * DE;
    int r0 = ry * 32, c0 = rx * 32;
    #pragma unroll
    for (int i = 0; i < 32; i += 8)
      tile[ty + i][tx] = in[bo + (size_t)(r0 + ty + i) * DE + (c0 + tx)];
    __syncthreads();
    #pragma unroll
    for (int i = 0; i < 32; i += 8) {
      float vv = tile[tx][ty + i];
      unsigned short hh = f2bf(vv);
      size_t oidx = bo + (size_t)(c0 + ty + i) * DM + (r0 + tx);
      if (which == 0)      { wqh[oidx] = hh; wql[oidx] = f2bf(vv - bf2f(hh)); }
      else if (which == 1) { wkh[oidx] = hh; wkl[oidx] = f2bf(vv - bf2f(hh)); }
      else                 { wvh[oidx] = hh; }
    }
  } else {
    int rem = f - 12288;       // o: [2048 n][2048 d] -> otb[d][n]
    int ry = rem >> 6, rx = rem & 63;
    int r0 = ry * 32, c0 = rx * 32;
    #pragma unroll
    for (int i = 0; i < 32; i += 8)
      tile[ty + i][tx] = o[(size_t)(r0 + ty + i) * DM + (c0 + tx)];
    __syncthreads();
    #pragma unroll
    for (int i = 0; i < 32; i += 8)
      otb[(size_t)(c0 + ty + i) * DM + (r0 + tx)] = f2bf(tile[tx][ty + i]);
  }
}

// ---------------- RoPE tables ----------------
__global__ void k_rope_tables(const float* __restrict__ theta_p,
                              float* __restrict__ cost, float* __restrict__ sint) {
  int s = blockIdx.x, j = threadIdx.x;
  float theta = theta_p[0];
  float rate = powf(theta, -(float)j * (1.0f / (float)DR));
  float ang = (float)s * rate;
  cost[s * DR + j] = cosf(ang);
  sint[s * DR + j] = sinf(ang);
}

// ---------------- merged q/k/v projection GEMM, 2-phase dbuf, 2x2 wave decomp ----------------
__launch_bounds__(256)
__global__ void k_projall(const unsigned short* __restrict__ xh, const unsigned short* __restrict__ xl,
                          const unsigned short* __restrict__ wqh, const unsigned short* __restrict__ wql,
                          const unsigned short* __restrict__ wkh, const unsigned short* __restrict__ wkl,
                          const unsigned short* __restrict__ wvh,
                          unsigned short* __restrict__ rqh, unsigned short* __restrict__ rql,
                          unsigned short* __restrict__ rkh, unsigned short* __restrict__ rkl,
                          unsigned short* __restrict__ vstt,
                          const float* __restrict__ cost, const float* __restrict__ sint) {
  __shared__ unsigned short Ahs[2][128 * 32];
  __shared__ unsigned short Als[2][128 * 32];
  __shared__ unsigned short Bhs[2][128 * 32];
  __shared__ unsigned short Bls[2][128 * 32];
  int mt = blockIdx.x;
  int mat = blockIdx.y >> 4, h = blockIdx.y & 15;
  bool split = (mat < 2);
  const unsigned short* wph = (mat == 0 ? wqh : (mat == 1 ? wkh : wvh)) + (size_t)h * DE * DM;
  const unsigned short* wpl = (mat == 0 ? wql : wkl) + (size_t)h * DE * DM;  // unused if mat==2
  int m0 = mt * 128;
  int tid = threadIdx.x, lane = tid & 63, wid = tid >> 6;
  int wr = wid >> 1, wc = wid & 1;

  f32x4 zero = {0.f, 0.f, 0.f, 0.f};
  f32x4 acc[4][4];
  #pragma unroll
  for (int i = 0; i < 4; ++i)
    #pragma unroll
    for (int j = 0; j < 4; ++j) acc[i][j] = zero;

  auto STAGE = [&](int buf, int k0) {
    #pragma unroll
    for (int p = 0; p < 2; ++p) {
      int r = p * 64 + wid * 16 + (lane >> 2);
      int c = ((lane & 3) ^ ((r >> 1) & 3)) * 8;     // inverse-swizzled global chunk
      int ld = r * 32 + (lane & 3) * 8;              // linear LDS dest
      gld16(&xh[(size_t)(m0 + r) * DM + k0 + c], &Ahs[buf][ld]);
      gld16(&wph[(size_t)r * DM + k0 + c], &Bhs[buf][ld]);
      if (split) {
        gld16(&xl[(size_t)(m0 + r) * DM + k0 + c], &Als[buf][ld]);
        gld16(&wpl[(size_t)r * DM + k0 + c], &Bls[buf][ld]);
      }
    }
  };

  const int NT = DM / 32;  // 64
  STAGE(0, 0);
  int cl_ = lane & 15;
  int chunk = lane >> 4;
  #pragma unroll 2
  for (int t = 0; t < NT; ++t) {
    int buf = t & 1;
    __syncthreads();                       // drains vmcnt(0): tile t staged; prev reads done
    if (t + 1 < NT) STAGE(buf ^ 1, (t + 1) * 32);   // loads fly during compute
    bf16x8 ah[4], al[4], bh[4], bl[4];
    #pragma unroll
    for (int mf = 0; mf < 4; ++mf) {
      int row = wr * 64 + mf * 16 + cl_;
      int off = row * 32 + ((chunk ^ ((row >> 1) & 3)) * 8);
      ah[mf] = *(const bf16x8*)&Ahs[buf][off];
      if (split) al[mf] = *(const bf16x8*)&Als[buf][off];
    }
    #pragma unroll
    for (int nf = 0; nf < 4; ++nf) {
      int nfi = wc * 2 + (nf & 1) + (nf >> 1) * 4;
      int row = nfi * 16 + cl_;
      int off = row * 32 + ((chunk ^ ((row >> 1) & 3)) * 8);
      bh[nf] = *(const bf16x8*)&Bhs[buf][off];
      if (split) bl[nf] = *(const bf16x8*)&Bls[buf][off];
    }
    if (split) {
      #pragma unroll
      for (int mf = 0; mf < 4; ++mf)
        #pragma unroll
        for (int nf = 0; nf < 4; ++nf) {
          acc[mf][nf] = __builtin_amdgcn_mfma_f32_16x16x32_bf16(ah[mf], bh[nf], acc[mf][nf], 0, 0, 0);
          acc[mf][nf] = __builtin_amdgcn_mfma_f32_16x16x32_bf16(al[mf], bh[nf], acc[mf][nf], 0, 0, 0);
          acc[mf][nf] = __builtin_amdgcn_mfma_f32_16x16x32_bf16(ah[mf], bl[nf], acc[mf][nf], 0, 0, 0);
        }
    } else {
      #pragma unroll
      for (int mf = 0; mf < 4; ++mf)
        #pragma unroll
        for (int nf = 0; nf < 4; ++nf)
          acc[mf][nf] = __builtin_amdgcn_mfma_f32_16x16x32_bf16(ah[mf], bh[nf], acc[mf][nf], 0, 0, 0);
    }
  }

  int cl = lane & 15, rl = (lane >> 4) * 4;
  if (mat == 2) {
    #pragma unroll
    for (int mf = 0; mf < 4; ++mf)
      #pragma unroll
      for (int nf = 0; nf < 4; ++nf) {
        int nfi = wc * 2 + (nf & 1) + (nf >> 1) * 4;
        #pragma unroll
        for (int j = 0; j < 4; ++j) {
          int s = m0 + wr * 64 + mf * 16 + rl + j;
          int e = nfi * 16 + cl;
          vstt[((size_t)h * DE + e) * SEQ + s] = f2bf(acc[mf][nf][j]);
        }
      }
  } else {
    unsigned short* oh = (mat == 0) ? rqh : rkh;
    unsigned short* ol = (mat == 0) ? rql : rkl;
    const float qsc = 0.2973017787506803f;  // 128^-0.25
    #pragma unroll
    for (int mf = 0; mf < 4; ++mf)
      #pragma unroll
      for (int nf = 0; nf < 2; ++nf)     // pair (nf, nf+2): cols e and e+64
        #pragma unroll
        for (int j = 0; j < 4; ++j) {
          int s = m0 + wr * 64 + mf * 16 + rl + j;
          int e = wc * 32 + (nf & 1) * 16 + cl;  // 0..63
          float x1 = acc[mf][nf][j];
          float x2 = acc[mf][nf + 2][j];
          float c  = cost[s * DR + e];
          float sn = sint[s * DR + e];
          float v1 = (c * x1 - sn * x2) * qsc;
          float v2 = (sn * x1 + c * x2) * qsc;
          size_t i1 = ((size_t)h * SEQ + s) * DE + e;
          size_t i2 = i1 + DR;
          unsigned short h1 = f2bf(v1), h2 = f2bf(v2);
          oh[i1] = h1; ol[i1] = f2bf(v1 - bf2f(h1));
          oh[i2] = h2; ol[i2] = f2bf(v2 - bf2f(h2));
        }
  }
}

// ---------------- causal flash attention (round-14 structure: QB=64, 256 thr, 2 blk/CU) ----------------
// SINGLE delta vs round-14: XCD-head grouping h = ((bid&7)<<1)|((bid>>3)&1) — each XCD's L2
// serves exactly 2 heads (3MB KV < 4MiB), so KV re-reads hit L2 not L3. Balanced LPT kept:
// blocks c and c+256 (co-resident on CU c) have qt summing to 31.
#define LOADKV(t0)                                                        \
  pkh0 = *(const int4*)&Kh[(size_t)((t0) + sk_r     ) * DE + sk_c];       \
  pkh1 = *(const int4*)&Kh[(size_t)((t0) + sk_r + 16) * DE + sk_c];       \
  pkh2 = *(const int4*)&Kh[(size_t)((t0) + sk_r + 32) * DE + sk_c];       \
  pkh3 = *(const int4*)&Kh[(size_t)((t0) + sk_r + 48) * DE + sk_c];       \
  pkl0 = *(const int4*)&Kl[(size_t)((t0) + sk_r     ) * DE + sk_c];       \
  pkl1 = *(const int4*)&Kl[(size_t)((t0) + sk_r + 16) * DE + sk_c];       \
  pkl2 = *(const int4*)&Kl[(size_t)((t0) + sk_r + 32) * DE + sk_c];       \
  pkl3 = *(const int4*)&Kl[(size_t)((t0) + sk_r + 48) * DE + sk_c];       \
  pvv0 = *(const int4*)&Vt[(size_t)(sv_r     ) * SEQ + (t0) + sv_c];      \
  pvv1 = *(const int4*)&Vt[(size_t)(sv_r + 32) * SEQ + (t0) + sv_c];      \
  pvv2 = *(const int4*)&Vt[(size_t)(sv_r + 64) * SEQ + (t0) + sv_c];      \
  pvv3 = *(const int4*)&Vt[(size_t)(sv_r + 96) * SEQ + (t0) + sv_c];

#define STOREKV()                                                         \
  *(int4*)&Khi[(sk_r     ) * LDK + sk_c] = pkh0;                          \
  *(int4*)&Khi[(sk_r + 16) * LDK + sk_c] = pkh1;                          \
  *(int4*)&Khi[(sk_r + 32) * LDK + sk_c] = pkh2;                          \
  *(int4*)&Khi[(sk_r + 48) * LDK + sk_c] = pkh3;                          \
  *(int4*)&Klo[(sk_r     ) * LDK + sk_c] = pkl0;                          \
  *(int4*)&Klo[(sk_r + 16) * LDK + sk_c] = pkl1;                          \
  *(int4*)&Klo[(sk_r + 32) * LDK + sk_c] = pkl2;                          \
  *(int4*)&Klo[(sk_r + 48) * LDK + sk_c] = pkl3;                          \
  *(int4*)&Vtl[(sv_r     ) * LDT + sv_c] = pvv0;                          \
  *(int4*)&Vtl[(sv_r + 32) * LDT + sv_c] = pvv1;                          \
  *(int4*)&Vtl[(sv_r + 64) * LDT + sv_c] = pvv2;                          \
  *(int4*)&Vtl[(sv_r + 96) * LDT + sv_c] = pvv3;

__launch_bounds__(256, 2)
__global__ void k_attn(const unsigned short* __restrict__ rqh, const unsigned short* __restrict__ rql,
                       const unsigned short* __restrict__ rkh, const unsigned short* __restrict__ rkl,
                       const unsigned short* __restrict__ vstt,
                       unsigned short* __restrict__ yb) {
  __shared__ unsigned short Khi[64 * LDK];
  __shared__ unsigned short Klo[64 * LDK];
  __shared__ unsigned short Vtl[128 * LDT];
  __shared__ unsigned short Pl[64 * LDT];
  int bid = blockIdx.x;
  int h = ((bid & 7) << 1) | ((bid >> 3) & 1);   // XCD-head grouping (single round-16 delta)
  int g = bid >> 4;
  int qt = (g < 16) ? (31 - g) : (g - 16);       // balanced LPT pairing
  int m0 = qt * 64;
  int tid = threadIdx.x, lane = tid & 63, wid = tid >> 6;
  const unsigned short* Qh = rqh + (size_t)h * SEQ * DE;
  const unsigned short* Ql = rql + (size_t)h * SEQ * DE;
  const unsigned short* Kh = rkh + (size_t)h * SEQ * DE;
  const unsigned short* Kl = rkl + (size_t)h * SEQ * DE;
  const unsigned short* Vt = vstt + (size_t)h * DE * SEQ;
  int cl = lane & 15, hi = lane >> 4;

  bf16x8 qfh[4], qfl[4];
  {
    int qrow = m0 + wid * 16 + cl;
    #pragma unroll
    for (int ks = 0; ks < 4; ++ks) {
      qfh[ks] = *(const bf16x8*)&Qh[(size_t)qrow * DE + ks * 32 + hi * 8];
      qfl[ks] = *(const bf16x8*)&Ql[(size_t)qrow * DE + ks * 32 + hi * 8];
    }
  }

  f32x4 zero = {0.f, 0.f, 0.f, 0.f};
  f32x4 acc[8];
  #pragma unroll
  for (int nf = 0; nf < 8; ++nf) acc[nf] = zero;
  float mrow[4], lrow[4];
  #pragma unroll
  for (int j = 0; j < 4; ++j) { mrow[j] = -3e38f; lrow[j] = 0.f; }

  int sk_r = tid >> 4, sk_c = (tid & 15) * 8;
  int sv_r = tid >> 3, sv_c = (tid & 7) * 8;

  int4 pkh0, pkh1, pkh2, pkh3, pkl0, pkl1, pkl2, pkl3, pvv0, pvv1, pvv2, pvv3;

  int ntiles = qt + 1;
  LOADKV(0)
  for (int t = 0; t < ntiles; ++t) {
    int t0 = t * 64;
    STOREKV()
    __syncthreads();
    if (t + 1 < ntiles) { LOADKV(t0 + 64) }

    f32x4 sacc[4];
    #pragma unroll
    for (int tf = 0; tf < 4; ++tf) sacc[tf] = zero;
    __builtin_amdgcn_s_setprio(1);
    #pragma unroll
    for (int ks = 0; ks < 4; ++ks) {
      int kk = ks * 32 + hi * 8;
      #pragma unroll
      for (int tf = 0; tf < 4; ++tf) {
        int r = (tf * 16 + cl) * LDK + kk;
        bf16x8 bh = *(const bf16x8*)&Khi[r];
        bf16x8 bl = *(const bf16x8*)&Klo[r];
        sacc[tf] = __builtin_amdgcn_mfma_f32_16x16x32_bf16(qfh[ks], bh, sacc[tf], 0, 0, 0);
        sacc[tf] = __builtin_amdgcn_mfma_f32_16x16x32_bf16(qfl[ks], bh, sacc[tf], 0, 0, 0);
        sacc[tf] = __builtin_amdgcn_mfma_f32_16x16x32_bf16(qfh[ks], bl, sacc[tf], 0, 0, 0);
      }
    }
    __builtin_amdgcn_s_setprio(0);
    if (t == ntiles - 1) {
      int sb = m0 + wid * 16 + hi * 4;
      #pragma unroll
      for (int tf = 0; tf < 4; ++tf) {
        int tc = t0 + tf * 16 + cl;
        #pragma unroll
        for (int j = 0; j < 4; ++j)
          if (tc > sb + j) sacc[tf][j] = -3e38f;
      }
    }
    // row maxima (always needed for the defer test)
    float mxa[4];
    #pragma unroll
    for (int j = 0; j < 4; ++j) {
      float mx = fmaxf(fmaxf(sacc[0][j], sacc[1][j]), fmaxf(sacc[2][j], sacc[3][j]));
      mx = fmaxf(mx, __shfl_xor(mx, 1));
      mx = fmaxf(mx, __shfl_xor(mx, 2));
      mx = fmaxf(mx, __shfl_xor(mx, 4));
      mx = fmaxf(mx, __shfl_xor(mx, 8));
      mxa[j] = mx;
    }
    bool need = (mxa[0] > mrow[0] + 8.f) || (mxa[1] > mrow[1] + 8.f) ||
                (mxa[2] > mrow[2] + 8.f) || (mxa[3] > mrow[3] + 8.f);
    if (__any(need)) {
      // full online-softmax update (rescale acc)
      #pragma unroll
      for (int j = 0; j < 4; ++j) {
        float mnew = fmaxf(mrow[j], mxa[j]);
        float sc = __expf(mrow[j] - mnew);
        float sum = 0.f;
        #pragma unroll
        for (int tf = 0; tf < 4; ++tf) {
          float p = __expf(sacc[tf][j] - mnew);
          sacc[tf][j] = p;
          sum += p;
        }
        sum += __shfl_xor(sum, 1);
        sum += __shfl_xor(sum, 2);
        sum += __shfl_xor(sum, 4);
        sum += __shfl_xor(sum, 8);
        lrow[j] = lrow[j] * sc + sum;
        mrow[j] = mnew;
        #pragma unroll
        for (int nf = 0; nf < 8; ++nf) acc[nf][j] *= sc;
      }
    } else {
      // deferred path: keep old max (P bounded by e^8), no acc rescale
      #pragma unroll
      for (int j = 0; j < 4; ++j) {
        float sum = 0.f;
        #pragma unroll
        for (int tf = 0; tf < 4; ++tf) {
          float p = __expf(sacc[tf][j] - mrow[j]);
          sacc[tf][j] = p;
          sum += p;
        }
        sum += __shfl_xor(sum, 1);
        sum += __shfl_xor(sum, 2);
        sum += __shfl_xor(sum, 4);
        sum += __shfl_xor(sum, 8);
        lrow[j] += sum;
      }
    }
    #pragma unroll
    for (int tf = 0; tf < 4; ++tf)
      #pragma unroll
      for (int j = 0; j < 4; ++j)
        Pl[(wid * 16 + hi * 4 + j) * LDT + tf * 16 + cl] = f2bf(sacc[tf][j]);
    __builtin_amdgcn_s_setprio(1);
    #pragma unroll
    for (int ks = 0; ks < 2; ++ks) {
      int kk = ks * 32 + hi * 8;
      bf16x8 a = *(const bf16x8*)&Pl[(wid * 16 + cl) * LDT + kk];
      #pragma unroll
      for (int nf = 0; nf < 8; ++nf) {
        bf16x8 b = *(const bf16x8*)&Vtl[(nf * 16 + cl) * LDT + kk];
        acc[nf] = __builtin_amdgcn_mfma_f32_16x16x32_bf16(a, b, acc[nf], 0, 0, 0);
      }
    }
    __builtin_amdgcn_s_setprio(0);
    __syncthreads();
  }

  #pragma unroll
  for (int j = 0; j < 4; ++j) {
    float inv = 1.0f / lrow[j];
    #pragma unroll
    for (int nf = 0; nf < 8; ++nf) acc[nf][j] *= inv;
  }
  #pragma unroll
  for (int nf = 0; nf < 8; ++nf)
    #pragma unroll
    for (int j = 0; j < 4; ++j) {
      int s = m0 + wid * 16 + hi * 4 + j;
      int e = nf * 16 + cl;
      yb[(size_t)s * DM + h * DE + e] = f2bf(acc[nf][j]);
    }
}

// ---------------- output projection GEMM (fp32 out), 2-phase dbuf BK=32, 2x2 decomp ----------------
__launch_bounds__(256)
__global__ void k_out(const unsigned short* __restrict__ yb,
                      const unsigned short* __restrict__ otb,
                      float* __restrict__ z) {
  __shared__ unsigned short Ahs[2][128 * 32];
  __shared__ unsigned short Bhs[2][128 * 32];
  int m0 = blockIdx.x * 128, n0 = blockIdx.y * 128;
  int tid = threadIdx.x, lane = tid & 63, wid = tid >> 6;
  int wr = wid >> 1, wc = wid & 1;
  f32x4 zero = {0.f, 0.f, 0.f, 0.f};
  f32x4 acc[4][4];
  #pragma unroll
  for (int i = 0; i < 4; ++i)
    #pragma unroll
    for (int j = 0; j < 4; ++j) acc[i][j] = zero;

  auto STAGE = [&](int buf, int k0) {
    #pragma unroll
    for (int p = 0; p < 2; ++p) {
      int r = p * 64 + wid * 16 + (lane >> 2);
      int c = ((lane & 3) ^ ((r >> 1) & 3)) * 8;
      int ld = r * 32 + (lane & 3) * 8;
      gld16(&yb[(size_t)(m0 + r) * DM + k0 + c], &Ahs[buf][ld]);
      gld16(&otb[(size_t)(n0 + r) * DM + k0 + c], &Bhs[buf][ld]);
    }
  };

  const int NT = DM / 32;
  STAGE(0, 0);
  int cl_ = lane & 15;
  int chunk = lane >> 4;
  #pragma unroll 2
  for (int t = 0; t < NT; ++t) {
    int buf = t & 1;
    __syncthreads();
    if (t + 1 < NT) STAGE(buf ^ 1, (t + 1) * 32);
    bf16x8 a[4], b[4];
    #pragma unroll
    for (int mf = 0; mf < 4; ++mf) {
      int row = wr * 64 + mf * 16 + cl_;
      a[mf] = *(const bf16x8*)&Ahs[buf][row * 32 + ((chunk ^ ((row >> 1) & 3)) * 8)];
    }
    #pragma unroll
    for (int nf = 0; nf < 4; ++nf) {
      int nfi = wc * 2 + (nf & 1) + (nf >> 1) * 4;
      int row = nfi * 16 + cl_;
      b[nf] = *(const bf16x8*)&Bhs[buf][row * 32 + ((chunk ^ ((row >> 1) & 3)) * 8)];
    }
    #pragma unroll
    for (int mf = 0; mf < 4; ++mf)
      #pragma unroll
      for (int nf = 0; nf < 4; ++nf)
        acc[mf][nf] = __builtin_amdgcn_mfma_f32_16x16x32_bf16(a[mf], b[nf], acc[mf][nf], 0, 0, 0);
  }
  int cl = lane & 15, rl = (lane >> 4) * 4;
  #pragma unroll
  for (int mf = 0; mf < 4; ++mf)
    #pragma unroll
    for (int nf = 0; nf < 4; ++nf) {
      int nfi = wc * 2 + (nf & 1) + (nf >> 1) * 4;
      #pragma unroll
      for (int j = 0; j < 4; ++j) {
        int s = m0 + wr * 64 + mf * 16 + rl + j;
        int d = n0 + nfi * 16 + cl;
        z[(size_t)s * DM + d] = acc[mf][nf][j];
      }
    }
}

extern "C" void kernel_launch(void* const* d_in, const int* in_sizes, int n_in,
                              void* d_out, int out_size, void* d_ws, size_t ws_size,
                              hipStream_t stream) {
  const float* x  = (const float*)d_in[0];
  const float* q  = (const float*)d_in[1];
  const float* k  = (const float*)d_in[2];
  const float* v  = (const float*)d_in[3];
  const float* o  = (const float*)d_in[4];
  const float* th = (const float*)d_in[5];
  float* z = (float*)d_out;
  char* ws = (char*)d_ws;
  const size_t MB = 1024 * 1024;
  unsigned short* xh  = (unsigned short*)(ws);            // 0
  unsigned short* xl  = (unsigned short*)(ws + 8 * MB);   // 8
  unsigned short* wqh = (unsigned short*)(ws + 16 * MB);  // 16
  unsigned short* wql = (unsigned short*)(ws + 24 * MB);  // 24
  unsigned short* wkh = (unsigned short*)(ws + 32 * MB);  // 32
  unsigned short* wkl = (unsigned short*)(ws + 40 * MB);  // 40
  unsigned short* wvh = (unsigned short*)(ws + 48 * MB);  // 48
  unsigned short* rqh = (unsigned short*)(ws + 56 * MB);  // 56
  unsigned short* rql = (unsigned short*)(ws + 64 * MB);  // 64
  unsigned short* rkh = (unsigned short*)(ws + 72 * MB);  // 72
  unsigned short* rkl = (unsigned short*)(ws + 80 * MB);  // 80
  unsigned short* vst = (unsigned short*)(ws + 88 * MB);  // 88
  float* cost = (float*)(ws + 96 * MB);                   // 96
  float* sint = (float*)(ws + 96 * MB + 512 * 1024);
  unsigned short* otb = (unsigned short*)(ws + 98 * MB);  // 98 (written by prep, read by k_out)
  // alias over dead weight buffer (stream-ordered):
  unsigned short* yb  = (unsigned short*)(ws + 16 * MB);  // over wqh, written after proj

  dim3 tb(32, 8);
  k_rope_tables<<<SEQ, DR, 0, stream>>>(th, cost, sint);
  k_split<<<2048, 256, 0, stream>>>(x, xh, xl, SEQ * DM / 4);
  k_prep_all<<<16384, tb, 0, stream>>>(q, k, v, o, wqh, wql, wkh, wkl, wvh, otb);
  k_projall<<<dim3(16, 48), 256, 0, stream>>>(xh, xl, wqh, wql, wkh, wkl, wvh,
                                              rqh, rql, rkh, rkl, vst, cost, sint);
  k_attn<<<512, 256, 0, stream>>>(rqh, rql, rkh, rkl, vst, yb);
  k_out<<<dim3(16, 16), 256, 0, stream>>>(yb, otb, z);
}

// Round 17
// 304.801 us; speedup vs baseline: 1.0660x; 1.0224x over previous
//
#include <hip/hip_runtime.h>
#include <hip/hip_bf16.h>

#define SEQ 2048
#define DM  2048
#define NH  16
#define DE  128
#define DR  64
#define LDT 72    // padded LDS row stride (elements) — k_attn
#define LDK 136

typedef __attribute__((ext_vector_type(8))) short bf16x8;
typedef __attribute__((ext_vector_type(4))) float f32x4;

__device__ __forceinline__ unsigned short f2bf(float f) {
  unsigned u = __float_as_uint(f);
  u += 0x7fff + ((u >> 16) & 1);   // RNE
  return (unsigned short)(u >> 16);
}
__device__ __forceinline__ float bf2f(unsigned short h) {
  return __uint_as_float((unsigned)h << 16);
}

// async global->LDS, 16B per lane. LDS dest = wave-uniform base + lane*16.
__device__ __forceinline__ void gld16(const unsigned short* g, unsigned short* l) {
  __builtin_amdgcn_global_load_lds(
      (const __attribute__((address_space(1))) unsigned int*)g,
      (__attribute__((address_space(3))) unsigned int*)l, 16, 0, 0);
}

// ---------------- fused prep: weight transposes + x hi/lo split + RoPE tables ----------------
// flat grid 17920, block (32,8):
//   [0,12288)      q/k split-transpose + v transpose (z=f>>8: which=z>>4, h=z&15; 64y x 4x tiles)
//   [12288,16384)  o transpose (64y x 64x tiles)
//   [16384,17408)  x fp32 -> (hi,lo) bf16 split (1024 blocks x 1024 float4)
//   [17408,17920)  RoPE cos/sin tables (512 blocks x 256 entries)
__global__ void k_prep_all(const float* __restrict__ q, const float* __restrict__ k,
                           const float* __restrict__ v, const float* __restrict__ o,
                           const float* __restrict__ x, const float* __restrict__ theta_p,
                           unsigned short* __restrict__ wqh, unsigned short* __restrict__ wql,
                           unsigned short* __restrict__ wkh, unsigned short* __restrict__ wkl,
                           unsigned short* __restrict__ wvh, unsigned short* __restrict__ otb,
                           unsigned short* __restrict__ xh, unsigned short* __restrict__ xl,
                           float* __restrict__ cost, float* __restrict__ sint) {
  __shared__ float tile[32][33];
  int f = blockIdx.x;
  int tx = threadIdx.x, ty = threadIdx.y;
  int tid = ty * 32 + tx;
  if (f < 12288) {
    int z = f >> 8;            // 0..47
    int rem = f & 255;         // 64 y-tiles x 4 x-tiles
    int ry = rem >> 2, rx = rem & 3;
    int which = z >> 4, h = z & 15;
    const float* in = (which == 0) ? q : (which == 1) ? k : v;
    size_t bo = (size_t)h * DM * DE;
    int r0 = ry * 32, c0 = rx * 32;
    #pragma unroll
    for (int i = 0; i < 32; i += 8)
      tile[ty + i][tx] = in[bo + (size_t)(r0 + ty + i) * DE + (c0 + tx)];
    __syncthreads();
    #pragma unroll
    for (int i = 0; i < 32; i += 8) {
      float vv = tile[tx][ty + i];
      unsigned short hh = f2bf(vv);
      size_t oidx = bo + (size_t)(c0 + ty + i) * DM + (r0 + tx);
      if (which == 0)      { wqh[oidx] = hh; wql[oidx] = f2bf(vv - bf2f(hh)); }
      else if (which == 1) { wkh[oidx] = hh; wkl[oidx] = f2bf(vv - bf2f(hh)); }
      else                 { wvh[oidx] = hh; }
    }
  } else if (f < 16384) {
    int rem = f - 12288;       // o: [2048 n][2048 d] -> otb[d][n]
    int ry = rem >> 6, rx = rem & 63;
    int r0 = ry * 32, c0 = rx * 32;
    #pragma unroll
    for (int i = 0; i < 32; i += 8)
      tile[ty + i][tx] = o[(size_t)(r0 + ty + i) * DM + (c0 + tx)];
    __syncthreads();
    #pragma unroll
    for (int i = 0; i < 32; i += 8)
      otb[(size_t)(c0 + ty + i) * DM + (r0 + tx)] = f2bf(tile[tx][ty + i]);
  } else if (f < 17408) {
    int rem = f - 16384;       // x split: 1024 float4 per block
    int base = rem * 1024;
    #pragma unroll
    for (int it = 0; it < 4; ++it) {
      int idx = base + it * 256 + tid;
      float4 vv = ((const float4*)x)[idx];
      ushort4 hh, ll;
      hh.x = f2bf(vv.x); ll.x = f2bf(vv.x - bf2f(hh.x));
      hh.y = f2bf(vv.y); ll.y = f2bf(vv.y - bf2f(hh.y));
      hh.z = f2bf(vv.z); ll.z = f2bf(vv.z - bf2f(hh.z));
      hh.w = f2bf(vv.w); ll.w = f2bf(vv.w - bf2f(hh.w));
      ((ushort4*)xh)[idx] = hh;
      ((ushort4*)xl)[idx] = ll;
    }
  } else {
    int rem = f - 17408;       // rope: 4 s-rows x 64 j per block
    int s = rem * 4 + (tid >> 6);
    int j = tid & 63;
    float theta = theta_p[0];
    float rate = powf(theta, -(float)j * (1.0f / (float)DR));
    float ang = (float)s * rate;
    cost[s * DR + j] = cosf(ang);
    sint[s * DR + j] = sinf(ang);
  }
}

// ---------------- merged q/k/v projection GEMM, 2-phase dbuf, 2x2 wave decomp ----------------
__launch_bounds__(256)
__global__ void k_projall(const unsigned short* __restrict__ xh, const unsigned short* __restrict__ xl,
                          const unsigned short* __restrict__ wqh, const unsigned short* __restrict__ wql,
                          const unsigned short* __restrict__ wkh, const unsigned short* __restrict__ wkl,
                          const unsigned short* __restrict__ wvh,
                          unsigned short* __restrict__ rqh, unsigned short* __restrict__ rql,
                          unsigned short* __restrict__ rkh, unsigned short* __restrict__ rkl,
                          unsigned short* __restrict__ vstt,
                          const float* __restrict__ cost, const float* __restrict__ sint) {
  __shared__ unsigned short Ahs[2][128 * 32];
  __shared__ unsigned short Als[2][128 * 32];
  __shared__ unsigned short Bhs[2][128 * 32];
  __shared__ unsigned short Bls[2][128 * 32];
  int mt = blockIdx.x;
  int mat = blockIdx.y >> 4, h = blockIdx.y & 15;
  bool split = (mat < 2);
  const unsigned short* wph = (mat == 0 ? wqh : (mat == 1 ? wkh : wvh)) + (size_t)h * DE * DM;
  const unsigned short* wpl = (mat == 0 ? wql : wkl) + (size_t)h * DE * DM;  // unused if mat==2
  int m0 = mt * 128;
  int tid = threadIdx.x, lane = tid & 63, wid = tid >> 6;
  int wr = wid >> 1, wc = wid & 1;

  f32x4 zero = {0.f, 0.f, 0.f, 0.f};
  f32x4 acc[4][4];
  #pragma unroll
  for (int i = 0; i < 4; ++i)
    #pragma unroll
    for (int j = 0; j < 4; ++j) acc[i][j] = zero;

  auto STAGE = [&](int buf, int k0) {
    #pragma unroll
    for (int p = 0; p < 2; ++p) {
      int r = p * 64 + wid * 16 + (lane >> 2);
      int c = ((lane & 3) ^ ((r >> 1) & 3)) * 8;     // inverse-swizzled global chunk
      int ld = r * 32 + (lane & 3) * 8;              // linear LDS dest
      gld16(&xh[(size_t)(m0 + r) * DM + k0 + c], &Ahs[buf][ld]);
      gld16(&wph[(size_t)r * DM + k0 + c], &Bhs[buf][ld]);
      if (split) {
        gld16(&xl[(size_t)(m0 + r) * DM + k0 + c], &Als[buf][ld]);
        gld16(&wpl[(size_t)r * DM + k0 + c], &Bls[buf][ld]);
      }
    }
  };

  const int NT = DM / 32;  // 64
  STAGE(0, 0);
  int cl_ = lane & 15;
  int chunk = lane >> 4;
  #pragma unroll 2
  for (int t = 0; t < NT; ++t) {
    int buf = t & 1;
    __syncthreads();                       // drains vmcnt(0): tile t staged; prev reads done
    if (t + 1 < NT) STAGE(buf ^ 1, (t + 1) * 32);   // loads fly during compute
    bf16x8 ah[4], al[4], bh[4], bl[4];
    #pragma unroll
    for (int mf = 0; mf < 4; ++mf) {
      int row = wr * 64 + mf * 16 + cl_;
      int off = row * 32 + ((chunk ^ ((row >> 1) & 3)) * 8);
      ah[mf] = *(const bf16x8*)&Ahs[buf][off];
      if (split) al[mf] = *(const bf16x8*)&Als[buf][off];
    }
    #pragma unroll
    for (int nf = 0; nf < 4; ++nf) {
      int nfi = wc * 2 + (nf & 1) + (nf >> 1) * 4;
      int row = nfi * 16 + cl_;
      int off = row * 32 + ((chunk ^ ((row >> 1) & 3)) * 8);
      bh[nf] = *(const bf16x8*)&Bhs[buf][off];
      if (split) bl[nf] = *(const bf16x8*)&Bls[buf][off];
    }
    if (split) {
      #pragma unroll
      for (int mf = 0; mf < 4; ++mf)
        #pragma unroll
        for (int nf = 0; nf < 4; ++nf) {
          acc[mf][nf] = __builtin_amdgcn_mfma_f32_16x16x32_bf16(ah[mf], bh[nf], acc[mf][nf], 0, 0, 0);
          acc[mf][nf] = __builtin_amdgcn_mfma_f32_16x16x32_bf16(al[mf], bh[nf], acc[mf][nf], 0, 0, 0);
          acc[mf][nf] = __builtin_amdgcn_mfma_f32_16x16x32_bf16(ah[mf], bl[nf], acc[mf][nf], 0, 0, 0);
        }
    } else {
      #pragma unroll
      for (int mf = 0; mf < 4; ++mf)
        #pragma unroll
        for (int nf = 0; nf < 4; ++nf)
          acc[mf][nf] = __builtin_amdgcn_mfma_f32_16x16x32_bf16(ah[mf], bh[nf], acc[mf][nf], 0, 0, 0);
    }
  }

  int cl = lane & 15, rl = (lane >> 4) * 4;
  if (mat == 2) {
    #pragma unroll
    for (int mf = 0; mf < 4; ++mf)
      #pragma unroll
      for (int nf = 0; nf < 4; ++nf) {
        int nfi = wc * 2 + (nf & 1) + (nf >> 1) * 4;
        #pragma unroll
        for (int j = 0; j < 4; ++j) {
          int s = m0 + wr * 64 + mf * 16 + rl + j;
          int e = nfi * 16 + cl;
          vstt[((size_t)h * DE + e) * SEQ + s] = f2bf(acc[mf][nf][j]);
        }
      }
  } else {
    unsigned short* oh = (mat == 0) ? rqh : rkh;
    unsigned short* ol = (mat == 0) ? rql : rkl;
    const float qsc = 0.2973017787506803f;  // 128^-0.25
    #pragma unroll
    for (int mf = 0; mf < 4; ++mf)
      #pragma unroll
      for (int nf = 0; nf < 2; ++nf)     // pair (nf, nf+2): cols e and e+64
        #pragma unroll
        for (int j = 0; j < 4; ++j) {
          int s = m0 + wr * 64 + mf * 16 + rl + j;
          int e = wc * 32 + (nf & 1) * 16 + cl;  // 0..63
          float x1 = acc[mf][nf][j];
          float x2 = acc[mf][nf + 2][j];
          float c  = cost[s * DR + e];
          float sn = sint[s * DR + e];
          float v1 = (c * x1 - sn * x2) * qsc;
          float v2 = (sn * x1 + c * x2) * qsc;
          size_t i1 = ((size_t)h * SEQ + s) * DE + e;
          size_t i2 = i1 + DR;
          unsigned short h1 = f2bf(v1), h2 = f2bf(v2);
          oh[i1] = h1; ol[i1] = f2bf(v1 - bf2f(h1));
          oh[i2] = h2; ol[i2] = f2bf(v2 - bf2f(h2));
        }
  }
}

// ---------------- causal flash attention (QB=64, 256 thr, 2 blk/CU) ----------------
// XCD-head grouping: h = ((bid&7)<<1)|((bid>>3)&1) — each XCD's L2 serves 2 heads (3MB < 4MiB).
// Balanced LPT: blocks c, c+256 co-resident, qt sums to 31. Named prefetch regs. Defer-max.
#define LOADKV(t0)                                                        \
  pkh0 = *(const int4*)&Kh[(size_t)((t0) + sk_r     ) * DE + sk_c];       \
  pkh1 = *(const int4*)&Kh[(size_t)((t0) + sk_r + 16) * DE + sk_c];       \
  pkh2 = *(const int4*)&Kh[(size_t)((t0) + sk_r + 32) * DE + sk_c];       \
  pkh3 = *(const int4*)&Kh[(size_t)((t0) + sk_r + 48) * DE + sk_c];       \
  pkl0 = *(const int4*)&Kl[(size_t)((t0) + sk_r     ) * DE + sk_c];       \
  pkl1 = *(const int4*)&Kl[(size_t)((t0) + sk_r + 16) * DE + sk_c];       \
  pkl2 = *(const int4*)&Kl[(size_t)((t0) + sk_r + 32) * DE + sk_c];       \
  pkl3 = *(const int4*)&Kl[(size_t)((t0) + sk_r + 48) * DE + sk_c];       \
  pvv0 = *(const int4*)&Vt[(size_t)(sv_r     ) * SEQ + (t0) + sv_c];      \
  pvv1 = *(const int4*)&Vt[(size_t)(sv_r + 32) * SEQ + (t0) + sv_c];      \
  pvv2 = *(const int4*)&Vt[(size_t)(sv_r + 64) * SEQ + (t0) + sv_c];      \
  pvv3 = *(const int4*)&Vt[(size_t)(sv_r + 96) * SEQ + (t0) + sv_c];

#define STOREKV()                                                         \
  *(int4*)&Khi[(sk_r     ) * LDK + sk_c] = pkh0;                          \
  *(int4*)&Khi[(sk_r + 16) * LDK + sk_c] = pkh1;                          \
  *(int4*)&Khi[(sk_r + 32) * LDK + sk_c] = pkh2;                          \
  *(int4*)&Khi[(sk_r + 48) * LDK + sk_c] = pkh3;                          \
  *(int4*)&Klo[(sk_r     ) * LDK + sk_c] = pkl0;                          \
  *(int4*)&Klo[(sk_r + 16) * LDK + sk_c] = pkl1;                          \
  *(int4*)&Klo[(sk_r + 32) * LDK + sk_c] = pkl2;                          \
  *(int4*)&Klo[(sk_r + 48) * LDK + sk_c] = pkl3;                          \
  *(int4*)&Vtl[(sv_r     ) * LDT + sv_c] = pvv0;                          \
  *(int4*)&Vtl[(sv_r + 32) * LDT + sv_c] = pvv1;                          \
  *(int4*)&Vtl[(sv_r + 64) * LDT + sv_c] = pvv2;                          \
  *(int4*)&Vtl[(sv_r + 96) * LDT + sv_c] = pvv3;

__launch_bounds__(256, 2)
__global__ void k_attn(const unsigned short* __restrict__ rqh, const unsigned short* __restrict__ rql,
                       const unsigned short* __restrict__ rkh, const unsigned short* __restrict__ rkl,
                       const unsigned short* __restrict__ vstt,
                       unsigned short* __restrict__ yb) {
  __shared__ unsigned short Khi[64 * LDK];
  __shared__ unsigned short Klo[64 * LDK];
  __shared__ unsigned short Vtl[128 * LDT];
  __shared__ unsigned short Pl[64 * LDT];
  int bid = blockIdx.x;
  int h = ((bid & 7) << 1) | ((bid >> 3) & 1);   // XCD-head grouping
  int g = bid >> 4;
  int qt = (g < 16) ? (31 - g) : (g - 16);       // balanced LPT pairing
  int m0 = qt * 64;
  int tid = threadIdx.x, lane = tid & 63, wid = tid >> 6;
  const unsigned short* Qh = rqh + (size_t)h * SEQ * DE;
  const unsigned short* Ql = rql + (size_t)h * SEQ * DE;
  const unsigned short* Kh = rkh + (size_t)h * SEQ * DE;
  const unsigned short* Kl = rkl + (size_t)h * SEQ * DE;
  const unsigned short* Vt = vstt + (size_t)h * DE * SEQ;
  int cl = lane & 15, hi = lane >> 4;

  bf16x8 qfh[4], qfl[4];
  {
    int qrow = m0 + wid * 16 + cl;
    #pragma unroll
    for (int ks = 0; ks < 4; ++ks) {
      qfh[ks] = *(const bf16x8*)&Qh[(size_t)qrow * DE + ks * 32 + hi * 8];
      qfl[ks] = *(const bf16x8*)&Ql[(size_t)qrow * DE + ks * 32 + hi * 8];
    }
  }

  f32x4 zero = {0.f, 0.f, 0.f, 0.f};
  f32x4 acc[8];
  #pragma unroll
  for (int nf = 0; nf < 8; ++nf) acc[nf] = zero;
  float mrow[4], lrow[4];
  #pragma unroll
  for (int j = 0; j < 4; ++j) { mrow[j] = -3e38f; lrow[j] = 0.f; }

  int sk_r = tid >> 4, sk_c = (tid & 15) * 8;
  int sv_r = tid >> 3, sv_c = (tid & 7) * 8;

  int4 pkh0, pkh1, pkh2, pkh3, pkl0, pkl1, pkl2, pkl3, pvv0, pvv1, pvv2, pvv3;

  int ntiles = qt + 1;
  LOADKV(0)
  for (int t = 0; t < ntiles; ++t) {
    int t0 = t * 64;
    STOREKV()
    __syncthreads();
    if (t + 1 < ntiles) { LOADKV(t0 + 64) }

    f32x4 sacc[4];
    #pragma unroll
    for (int tf = 0; tf < 4; ++tf) sacc[tf] = zero;
    __builtin_amdgcn_s_setprio(1);
    #pragma unroll
    for (int ks = 0; ks < 4; ++ks) {
      int kk = ks * 32 + hi * 8;
      #pragma unroll
      for (int tf = 0; tf < 4; ++tf) {
        int r = (tf * 16 + cl) * LDK + kk;
        bf16x8 bh = *(const bf16x8*)&Khi[r];
        bf16x8 bl = *(const bf16x8*)&Klo[r];
        sacc[tf] = __builtin_amdgcn_mfma_f32_16x16x32_bf16(qfh[ks], bh, sacc[tf], 0, 0, 0);
        sacc[tf] = __builtin_amdgcn_mfma_f32_16x16x32_bf16(qfl[ks], bh, sacc[tf], 0, 0, 0);
        sacc[tf] = __builtin_amdgcn_mfma_f32_16x16x32_bf16(qfh[ks], bl, sacc[tf], 0, 0, 0);
      }
    }
    __builtin_amdgcn_s_setprio(0);
    if (t == ntiles - 1) {
      int sb = m0 + wid * 16 + hi * 4;
      #pragma unroll
      for (int tf = 0; tf < 4; ++tf) {
        int tc = t0 + tf * 16 + cl;
        #pragma unroll
        for (int j = 0; j < 4; ++j)
          if (tc > sb + j) sacc[tf][j] = -3e38f;
      }
    }
    float mxa[4];
    #pragma unroll
    for (int j = 0; j < 4; ++j) {
      float mx = fmaxf(fmaxf(sacc[0][j], sacc[1][j]), fmaxf(sacc[2][j], sacc[3][j]));
      mx = fmaxf(mx, __shfl_xor(mx, 1));
      mx = fmaxf(mx, __shfl_xor(mx, 2));
      mx = fmaxf(mx, __shfl_xor(mx, 4));
      mx = fmaxf(mx, __shfl_xor(mx, 8));
      mxa[j] = mx;
    }
    bool need = (mxa[0] > mrow[0] + 8.f) || (mxa[1] > mrow[1] + 8.f) ||
                (mxa[2] > mrow[2] + 8.f) || (mxa[3] > mrow[3] + 8.f);
    if (__any(need)) {
      #pragma unroll
      for (int j = 0; j < 4; ++j) {
        float mnew = fmaxf(mrow[j], mxa[j]);
        float sc = __expf(mrow[j] - mnew);
        float sum = 0.f;
        #pragma unroll
        for (int tf = 0; tf < 4; ++tf) {
          float p = __expf(sacc[tf][j] - mnew);
          sacc[tf][j] = p;
          sum += p;
        }
        sum += __shfl_xor(sum, 1);
        sum += __shfl_xor(sum, 2);
        sum += __shfl_xor(sum, 4);
        sum += __shfl_xor(sum, 8);
        lrow[j] = lrow[j] * sc + sum;
        mrow[j] = mnew;
        #pragma unroll
        for (int nf = 0; nf < 8; ++nf) acc[nf][j] *= sc;
      }
    } else {
      #pragma unroll
      for (int j = 0; j < 4; ++j) {
        float sum = 0.f;
        #pragma unroll
        for (int tf = 0; tf < 4; ++tf) {
          float p = __expf(sacc[tf][j] - mrow[j]);
          sacc[tf][j] = p;
          sum += p;
        }
        sum += __shfl_xor(sum, 1);
        sum += __shfl_xor(sum, 2);
        sum += __shfl_xor(sum, 4);
        sum += __shfl_xor(sum, 8);
        lrow[j] += sum;
      }
    }
    #pragma unroll
    for (int tf = 0; tf < 4; ++tf)
      #pragma unroll
      for (int j = 0; j < 4; ++j)
        Pl[(wid * 16 + hi * 4 + j) * LDT + tf * 16 + cl] = f2bf(sacc[tf][j]);
    __builtin_amdgcn_s_setprio(1);
    #pragma unroll
    for (int ks = 0; ks < 2; ++ks) {
      int kk = ks * 32 + hi * 8;
      bf16x8 a = *(const bf16x8*)&Pl[(wid * 16 + cl) * LDT + kk];
      #pragma unroll
      for (int nf = 0; nf < 8; ++nf) {
        bf16x8 b = *(const bf16x8*)&Vtl[(nf * 16 + cl) * LDT + kk];
        acc[nf] = __builtin_amdgcn_mfma_f32_16x16x32_bf16(a, b, acc[nf], 0, 0, 0);
      }
    }
    __builtin_amdgcn_s_setprio(0);
    __syncthreads();
  }

  #pragma unroll
  for (int j = 0; j < 4; ++j) {
    float inv = 1.0f / lrow[j];
    #pragma unroll
    for (int nf = 0; nf < 8; ++nf) acc[nf][j] *= inv;
  }
  #pragma unroll
  for (int nf = 0; nf < 8; ++nf)
    #pragma unroll
    for (int j = 0; j < 4; ++j) {
      int s = m0 + wid * 16 + hi * 4 + j;
      int e = nf * 16 + cl;
      yb[(size_t)s * DM + h * DE + e] = f2bf(acc[nf][j]);
    }
}

// ---------------- output projection GEMM (fp32 out), 2-phase dbuf BK=32, 2x2 decomp ----------------
__launch_bounds__(256)
__global__ void k_out(const unsigned short* __restrict__ yb,
                      const unsigned short* __restrict__ otb,
                      float* __restrict__ z) {
  __shared__ unsigned short Ahs[2][128 * 32];
  __shared__ unsigned short Bhs[2][128 * 32];
  int m0 = blockIdx.x * 128, n0 = blockIdx.y * 128;
  int tid = threadIdx.x, lane = tid & 63, wid = tid >> 6;
  int wr = wid >> 1, wc = wid & 1;
  f32x4 zero = {0.f, 0.f, 0.f, 0.f};
  f32x4 acc[4][4];
  #pragma unroll
  for (int i = 0; i < 4; ++i)
    #pragma unroll
    for (int j = 0; j < 4; ++j) acc[i][j] = zero;

  auto STAGE = [&](int buf, int k0) {
    #pragma unroll
    for (int p = 0; p < 2; ++p) {
      int r = p * 64 + wid * 16 + (lane >> 2);
      int c = ((lane & 3) ^ ((r >> 1) & 3)) * 8;
      int ld = r * 32 + (lane & 3) * 8;
      gld16(&yb[(size_t)(m0 + r) * DM + k0 + c], &Ahs[buf][ld]);
      gld16(&otb[(size_t)(n0 + r) * DM + k0 + c], &Bhs[buf][ld]);
    }
  };

  const int NT = DM / 32;
  STAGE(0, 0);
  int cl_ = lane & 15;
  int chunk = lane >> 4;
  #pragma unroll 2
  for (int t = 0; t < NT; ++t) {
    int buf = t & 1;
    __syncthreads();
    if (t + 1 < NT) STAGE(buf ^ 1, (t + 1) * 32);
    bf16x8 a[4], b[4];
    #pragma unroll
    for (int mf = 0; mf < 4; ++mf) {
      int row = wr * 64 + mf * 16 + cl_;
      a[mf] = *(const bf16x8*)&Ahs[buf][row * 32 + ((chunk ^ ((row >> 1) & 3)) * 8)];
    }
    #pragma unroll
    for (int nf = 0; nf < 4; ++nf) {
      int nfi = wc * 2 + (nf & 1) + (nf >> 1) * 4;
      int row = nfi * 16 + cl_;
      b[nf] = *(const bf16x8*)&Bhs[buf][row * 32 + ((chunk ^ ((row >> 1) & 3)) * 8)];
    }
    #pragma unroll
    for (int mf = 0; mf < 4; ++mf)
      #pragma unroll
      for (int nf = 0; nf < 4; ++nf)
        acc[mf][nf] = __builtin_amdgcn_mfma_f32_16x16x32_bf16(a[mf], b[nf], acc[mf][nf], 0, 0, 0);
  }
  int cl = lane & 15, rl = (lane >> 4) * 4;
  #pragma unroll
  for (int mf = 0; mf < 4; ++mf)
    #pragma unroll
    for (int nf = 0; nf < 4; ++nf) {
      int nfi = wc * 2 + (nf & 1) + (nf >> 1) * 4;
      #pragma unroll
      for (int j = 0; j < 4; ++j) {
        int s = m0 + wr * 64 + mf * 16 + rl + j;
        int d = n0 + nfi * 16 + cl;
        z[(size_t)s * DM + d] = acc[mf][nf][j];
      }
    }
}

extern "C" void kernel_launch(void* const* d_in, const int* in_sizes, int n_in,
                              void* d_out, int out_size, void* d_ws, size_t ws_size,
                              hipStream_t stream) {
  const float* x  = (const float*)d_in[0];
  const float* q  = (const float*)d_in[1];
  const float* k  = (const float*)d_in[2];
  const float* v  = (const float*)d_in[3];
  const float* o  = (const float*)d_in[4];
  const float* th = (const float*)d_in[5];
  float* z = (float*)d_out;
  char* ws = (char*)d_ws;
  const size_t MB = 1024 * 1024;
  unsigned short* xh  = (unsigned short*)(ws);            // 0
  unsigned short* xl  = (unsigned short*)(ws + 8 * MB);   // 8
  unsigned short* wqh = (unsigned short*)(ws + 16 * MB);  // 16
  unsigned short* wql = (unsigned short*)(ws + 24 * MB);  // 24
  unsigned short* wkh = (unsigned short*)(ws + 32 * MB);  // 32
  unsigned short* wkl = (unsigned short*)(ws + 40 * MB);  // 40
  unsigned short* wvh = (unsigned short*)(ws + 48 * MB);  // 48
  unsigned short* rqh = (unsigned short*)(ws + 56 * MB);  // 56
  unsigned short* rql = (unsigned short*)(ws + 64 * MB);  // 64
  unsigned short* rkh = (unsigned short*)(ws + 72 * MB);  // 72
  unsigned short* rkl = (unsigned short*)(ws + 80 * MB);  // 80
  unsigned short* vst = (unsigned short*)(ws + 88 * MB);  // 88
  float* cost = (float*)(ws + 96 * MB);                   // 96
  float* sint = (float*)(ws + 96 * MB + 512 * 1024);
  unsigned short* otb = (unsigned short*)(ws + 98 * MB);  // 98 (written by prep, read by k_out)
  // alias over dead weight buffer (stream-ordered):
  unsigned short* yb  = (unsigned short*)(ws + 16 * MB);  // over wqh, written after proj

  dim3 tb(32, 8);
  k_prep_all<<<17920, tb, 0, stream>>>(q, k, v, o, x, th,
                                       wqh, wql, wkh, wkl, wvh, otb, xh, xl, cost, sint);
  k_projall<<<dim3(16, 48), 256, 0, stream>>>(xh, xl, wqh, wql, wkh, wkl, wvh,
                                              rqh, rql, rkh, rkl, vst, cost, sint);
  k_attn<<<512, 256, 0, stream>>>(rqh, rql, rkh, rkl, vst, yb);
  k_out<<<dim3(16, 16), 256, 0, stream>>>(yb, otb, z);
}